// Round 5
// baseline (3701.036 us; speedup 1.0000x reference)
//
#include <hip/hip_runtime.h>
#include <cstdint>
#include <cstddef>
#include <type_traits>
#include <utility>

typedef unsigned short u16;
typedef short short8 __attribute__((ext_vector_type(8)));
typedef __bf16 bf16x8 __attribute__((ext_vector_type(8)));
typedef float float4v __attribute__((ext_vector_type(4)));

// ---------- bf16 <-> f32 ----------
__device__ __forceinline__ float bf2f(u16 u) {
  union { uint32_t i; float f; } v; v.i = ((uint32_t)u) << 16; return v.f;
}
__device__ __forceinline__ u16 f2bf(float f) {
  union { uint32_t i; float f; } v; v.f = f;
  uint32_t u = v.i;
  return (u16)((u + 0x7FFFu + ((u >> 16) & 1u)) >> 16);
}

// ---------- fast transcendentals (saturate cleanly at +-inf) ----------
__device__ __forceinline__ float fsig(float x) {
  float e = __expf(-x);
  return __builtin_amdgcn_rcpf(1.0f + e);
}
__device__ __forceinline__ float ftanh(float x) {
  float e = __expf(2.0f * x);
  return 1.0f - 2.0f * __builtin_amdgcn_rcpf(e + 1.0f);
}

// ---------- barriers ----------
// LDS-only consistency (drain lgkmcnt, not vmcnt).
__device__ __forceinline__ void bar_lgkm() {
  __builtin_amdgcn_sched_barrier(0);
  asm volatile("s_waitcnt lgkmcnt(0)" ::: "memory");
  __builtin_amdgcn_s_barrier();
  __builtin_amdgcn_sched_barrier(0);
}
// Full drain (vm + lgkm) + barrier: before cross-CU flag release.
__device__ __forceinline__ void bar_vm() {
  __builtin_amdgcn_sched_barrier(0);
  asm volatile("s_waitcnt vmcnt(0) lgkmcnt(0)" ::: "memory");
  __builtin_amdgcn_s_barrier();
  __builtin_amdgcn_sched_barrier(0);
}
// Execution-only barrier: no waitcnt (used after flag poll; in-flight gx
// prefetch loads must NOT be drained here).
__device__ __forceinline__ void bar_only() {
  __builtin_amdgcn_sched_barrier(0);
  __builtin_amdgcn_s_barrier();
  __builtin_amdgcn_sched_barrier(0);
}

// ---------- MFMA wrapper: works whether builtin takes short8 or bf16x8 ----------
template <class V, class = void> struct MfmaTakesShort : std::false_type {};
template <class V>
struct MfmaTakesShort<V, std::void_t<decltype(__builtin_amdgcn_mfma_f32_16x16x32_bf16(
    std::declval<V>(), std::declval<V>(), std::declval<float4v>(), 0, 0, 0))>>
    : std::true_type {};

template <bool UseShort> struct MF {
  template <class V>
  static __device__ __forceinline__ float4v run(V a, V b, float4v c) {
    return __builtin_amdgcn_mfma_f32_16x16x32_bf16(a, b, c, 0, 0, 0);
  }
};
template <> struct MF<false> {
  template <class V>
  static __device__ __forceinline__ float4v run(V a, V b, float4v c) {
    return __builtin_amdgcn_mfma_f32_16x16x32_bf16(
        __builtin_bit_cast(bf16x8, a), __builtin_bit_cast(bf16x8, b), c, 0, 0, 0);
  }
};
__device__ __forceinline__ float4v mfma_bf16(short8 a, short8 b, float4v c) {
  return MF<MfmaTakesShort<short8>::value>::run(a, b, c);
}

// ============================================================================
// Weight conversion: f32 [2048][Kin] -> bf16 [2048][512], zero-padded
// ============================================================================
__global__ void k_cvt_wih(const float* __restrict__ w, u16* __restrict__ o, int Kin) {
  int id = blockIdx.x * 256 + threadIdx.x;   // 2048*512 total
  int n = id >> 9, k = id & 511;
  o[id] = (k < Kin) ? f2bf(w[(long)n * Kin + k]) : (u16)0;
}

// f32 -> bf16 straight convert (w_hh: 2*1024*256 = 524288 elems)
__global__ void k_cvt_whh(const float* __restrict__ w, u16* __restrict__ o) {
  int id = blockIdx.x * 256 + threadIdx.x;
  o[id] = f2bf(w[id]);
}

// ============================================================================
// proj[v][k][nf] = sum_cd emb_char[v][cd] * conv_w[nf][cd][k]   (f32 in, bf16 out)
// ============================================================================
__global__ void k_proj(const float* __restrict__ ec, const float* __restrict__ cw,
                       u16* __restrict__ proj) {
  int v = blockIdx.x, idx = threadIdx.x;
  if (idx >= 300) return;
  int k = idx / 100, nf = idx % 100;
  float s = 0.f;
  for (int cd = 0; cd < 100; cd++)
    s += ec[v * 100 + cd] * cw[(nf * 100 + cd) * 3 + k];
  proj[v * 300 + k * 100 + nf] = f2bf(s);
}

// ============================================================================
// word + pos embedding gather into bf16 x (cols 0..299 word, 400..499 pos,
// 500..511 zero). Char features (300..399) filled by k_charconv.
// ============================================================================
__global__ void k_embed(const int* __restrict__ iw, const int* __restrict__ ip,
                        const float* __restrict__ ew, const float* __restrict__ ep,
                        u16* __restrict__ x) {
  int row = blockIdx.x, j = threadIdx.x;
  u16 v;
  if (j < 300) v = f2bf(ew[(long)iw[row] * 300 + j]);
  else if (j < 400) return;
  else if (j < 500) v = f2bf(ep[ip[row] * 100 + (j - 400)]);
  else v = 0;
  x[row * 512 + j] = v;
}

// ============================================================================
// char conv via proj table in LDS: out[nf] = tanh(b + max_p sum_k proj)
// ============================================================================
__global__ __launch_bounds__(128) void k_charconv(const int* __restrict__ ic,
                                                  const u16* __restrict__ proj,
                                                  const float* __restrict__ cb,
                                                  u16* __restrict__ x) {
  __shared__ u16 pl[30000];
  __shared__ int ids[20];
  int tid = threadIdx.x;
  for (int i = tid; i < 15000; i += 128)
    ((uint32_t*)pl)[i] = ((const uint32_t*)proj)[i];
  float bias = (tid < 100) ? cb[tid] : 0.f;
  for (int r = 0; r < 16; r++) {
    int row = blockIdx.x * 16 + r;
    __syncthreads();  // covers pl load on first iter; protects ids reuse
    if (tid < 20) ids[tid] = ic[row * 20 + tid];
    __syncthreads();
    if (tid < 100) {
      float mx = -1e30f;
      for (int p = 0; p < 22; p++) {
        float s = 0.f;
#pragma unroll
        for (int k = 0; k < 3; k++) {
          int q = p + k - 2;
          if (q >= 0 && q < 20) s += bf2f(pl[ids[q] * 300 + k * 100 + tid]);
        }
        mx = fmaxf(mx, s);
      }
      x[row * 512 + 300 + tid] = f2bf(ftanh(mx + bias));
    }
  }
}

// ============================================================================
// GEMM  C[16384 x 2048] = A[16384 x 512](bf16) @ B[2048 x 512]^T + bias(f32)
// 128x128 tile, BK=64, 4 waves, 16x16x32 MFMA. C fp32 (tier A) or bf16 (tier B).
// ============================================================================
template <bool GXF32>
__global__ __launch_bounds__(256) void k_gemm(const u16* __restrict__ A,
                                              const u16* __restrict__ Bm,
                                              const float* __restrict__ bias,
                                              void* __restrict__ Cv) {
  __shared__ u16 lA[128 * 64];
  __shared__ u16 lB[128 * 64];
  int tid = threadIdx.x;
  int w = tid >> 6, l = tid & 63, q = l >> 4, c16 = l & 15;
  int wm = w >> 1, wn = w & 1;
  int m0 = blockIdx.y * 128, n0 = blockIdx.x * 128;
  float4v acc[4][4];
#pragma unroll
  for (int i = 0; i < 4; i++)
#pragma unroll
    for (int j = 0; j < 4; j++) acc[i][j] = (float4v){0.f, 0.f, 0.f, 0.f};

  for (int kk = 0; kk < 512; kk += 64) {
    __syncthreads();
#pragma unroll
    for (int j = 0; j < 4; j++) {
      int idx = j * 256 + tid;
      int m = idx >> 3, k8 = (idx & 7) * 8;
      *(short8*)(lA + idx * 8) = *(const short8*)(A + (long)(m0 + m) * 512 + kk + k8);
      *(short8*)(lB + idx * 8) = *(const short8*)(Bm + (long)(n0 + m) * 512 + kk + k8);
    }
    __syncthreads();
#pragma unroll
    for (int kt = 0; kt < 2; kt++) {
      short8 af[4], bfv[4];
#pragma unroll
      for (int mt = 0; mt < 4; mt++)
        af[mt] = *(const short8*)(lA + (wm * 64 + mt * 16 + c16) * 64 + kt * 32 + q * 8);
#pragma unroll
      for (int nt = 0; nt < 4; nt++)
        bfv[nt] = *(const short8*)(lB + (wn * 64 + nt * 16 + c16) * 64 + kt * 32 + q * 8);
#pragma unroll
      for (int mt = 0; mt < 4; mt++)
#pragma unroll
        for (int nt = 0; nt < 4; nt++)
          acc[mt][nt] = mfma_bf16(af[mt], bfv[nt], acc[mt][nt]);
    }
  }
#pragma unroll
  for (int mt = 0; mt < 4; mt++)
#pragma unroll
    for (int nt = 0; nt < 4; nt++) {
      int ng = n0 + wn * 64 + nt * 16 + c16;
      float bv = bias[ng];
#pragma unroll
      for (int r = 0; r < 4; r++) {
        long mg = m0 + wm * 64 + mt * 16 + q * 4 + r;
        float val = acc[mt][nt][r] + bv;
        if constexpr (GXF32) ((float*)Cv)[mg * 2048 + ng] = val;
        else ((u16*)Cv)[mg * 2048 + ng] = f2bf(val);
      }
    }
}

// ============================================================================
// LSTM recurrence, COLUMN-SPLIT + SPLIT-K PIPELINE.
// 16 blocks = 8 pairs (4 bg x 2 dir) x 2 halves; each block owns 128 h-cols.
//
// R4: R3's exchange chain (hx store -> vmcnt drain -> flag -> poll -> ingest
// -> ds round trip) sat fully on the critical path (~4-5k of 7.6k cy/step).
// Restructured so partner data is needed as LATE as possible:
//   ph0: issue gx(t) + mask loads (consumed in ph4 as adds, NOT as MFMA C:
//        R2's approach, viable now that the split halved register footprint)
//   ph1: own-half-K MFMA (4 kt x 4 g) from local hls — no partner dependency
//   ph2: tid0 polls partner flag(s-1); barrier WITHOUT vmcnt drain (gx
//        prefetch stays in flight)
//   ph3: partner-half-K MFMA, A-frags loaded DIRECTLY from hx (row-major
//        u64 pairs, agent scope) — no LDS round trip for partner h
//   ph4: nonlin, gate = acc + gx
//   ph5: own h -> hls[wr] (ds) ; bar_lgkm ; LDS readback -> hx row-major
//        (agent stores) ; output stores ; bar_vm ; tid0 releases flag(s)
// Slot parity s&1, flags fresh per step (memset per dispatch, replay-safe).
// Safety: I rewrite slot p at s+2 only after observing partner flag(s+1),
// which partner sets only after its ph3 read of slot p at s+1. Poll is
// iteration-capped -> sync bug fails absmax instead of hanging.
// Breg layout [g*8+j]: j=0..3 own-half k-tiles, j=4..7 partner-half
// (compile-time indices; rule #20).
// ============================================================================
template <bool GXF32, bool OUTF32>
__global__ __launch_bounds__(512, 2) void k_recur(
    const void* __restrict__ gxv, const u16* __restrict__ whh,
    const float* __restrict__ mask, void* __restrict__ outv,
    unsigned long long* __restrict__ hx, unsigned* __restrict__ flags) {
  __shared__ u16 hls[2][16 * 264];  // own-half h only; pad kills bank conflicts
  int tid = threadIdx.x;
  int w = tid >> 6, l = tid & 63, q = l >> 4, c16 = l & 15;
  int blk = blockIdx.x;
  int pair = blk & 7, half = blk >> 3;   // pair-mates land on same XCD
  int bg = pair >> 1, d = pair & 1;
  int b0 = bg * 16;
  int ht = half * 8 + w;                 // global h-coltile 0..15
  const u16* Wd = whh + d * (1024 * 256);

  for (int i = tid; i < 16 * 264; i += 512) hls[0][i] = 0;

  // B fragments: [g*8+j], j<4 own-half k-tiles, j>=4 partner-half k-tiles.
  short8 Breg[32];
#pragma unroll
  for (int g = 0; g < 4; g++)
#pragma unroll
    for (int j = 0; j < 8; j++) {
      int ktg = (j < 4) ? (half * 4 + j) : ((half ^ 1) * 4 + (j - 4));
      Breg[g * 8 + j] =
          *(const short8*)(Wd + ((g * 16 + ht) * 16 + c16) * 256 + ktg * 32 + q * 8);
    }

  float c_[4] = {0.f, 0.f, 0.f, 0.f};
  unsigned hprev[2] = {0u, 0u};  // packed bf16 of this lane's previous hn (4 rows)
  __syncthreads();

  const float* gxf = (const float*)gxv;
  const u16* gxh = (const u16*)gxv;
  float* outf = (float*)outv;
  u16* outh = (u16*)outv;

  // step-invariant per-lane element offsets (row-major GX), row = b0+q*4+r
  int rb[4];
#pragma unroll
  for (int r = 0; r < 4; r++)
    rb[r] = (b0 + q * 4 + r) * 524288 + d * 1024 + ht * 16 + c16;
  const float* mrow = mask + (b0 + q * 4) * 256;

#pragma unroll 1
  for (int s = 0; s < 256; s++) {
    int t = d ? (255 - s) : s;
    const u16* hrd = hls[s & 1];
    u16* hwr = hls[(s & 1) ^ 1];

    // ---- ph0: issue gx + mask loads; consumed in ph4 (adds), ~1500cy away
    float m4[4];
#pragma unroll
    for (int r = 0; r < 4; r++) m4[r] = mrow[r * 256 + t];
    float gxc[16];  // [g*4+r]
    if constexpr (GXF32) {
      const float* gxs = gxf + (size_t)t * 2048;
#pragma unroll
      for (int r = 0; r < 4; r++) {
        const float* p = gxs + rb[r];
#pragma unroll
        for (int g = 0; g < 4; g++) gxc[g * 4 + r] = p[g * 256];  // imm offset
      }
    } else {
      const u16* gxs = gxh + (size_t)t * 2048;
#pragma unroll
      for (int r = 0; r < 4; r++) {
        const u16* p = gxs + rb[r];
#pragma unroll
        for (int g = 0; g < 4; g++) gxc[g * 4 + r] = bf2f(p[g * 256]);
      }
    }
    __builtin_amdgcn_sched_barrier(0);  // pin load issue here

    // ---- ph1: own-half-K MFMA (no partner dependency)
    float4v acc[4];
#pragma unroll
    for (int g = 0; g < 4; g++) acc[g] = (float4v){0.f, 0.f, 0.f, 0.f};
#pragma unroll
    for (int ktl = 0; ktl < 4; ktl++) {
      short8 a = *(const short8*)(hrd + c16 * 264 + half * 128 + ktl * 32 + q * 8);
#pragma unroll
      for (int g = 0; g < 4; g++)
        acc[g] = mfma_bf16(a, Breg[g * 8 + ktl], acc[g]);
    }

    if (s > 0) {
      // ---- ph2: wait partner h(s-1) (flag set during partner's ph5 of s-1)
      if (tid == 0) {
        unsigned idx = (unsigned)((s - 1) * 16 + pair * 2 + (half ^ 1));
        unsigned cnt = 0;
        while (__hip_atomic_load(&flags[idx], __ATOMIC_ACQUIRE,
                                 __HIP_MEMORY_SCOPE_AGENT) == 0u) {
          if (++cnt > 1000000u) break;  // fail visibly (absmax), don't hang
          __builtin_amdgcn_s_sleep(1);
        }
      }
      bar_only();  // no waitcnt: gx prefetch stays in flight

      // ---- ph3: partner-half-K MFMA, A-frags straight from hx (row-major)
      const unsigned long long* ps =
          hx + ((size_t)(pair * 2 + ((s - 1) & 1)) * 2 + (half ^ 1)) * 512;
#pragma unroll
      for (int ktl = 0; ktl < 4; ktl++) {
        int bi = c16 * 32 + ktl * 8 + q * 2;
        unsigned long long v0 =
            __hip_atomic_load(&ps[bi], __ATOMIC_RELAXED, __HIP_MEMORY_SCOPE_AGENT);
        unsigned long long v1 =
            __hip_atomic_load(&ps[bi + 1], __ATOMIC_RELAXED, __HIP_MEMORY_SCOPE_AGENT);
        union { unsigned long long u[2]; short8 s8; } uu;
        uu.u[0] = v0; uu.u[1] = v1;
#pragma unroll
        for (int g = 0; g < 4; g++)
          acc[g] = mfma_bf16(uu.s8, Breg[g * 8 + 4 + ktl], acc[g]);
      }
    }

    // ---- ph4: nonlinearity; gate = acc + gx (gx latency hidden by ph1-ph3)
    unsigned p0 = 0u, p1 = 0u;
    float hfv[4];
#pragma unroll
    for (int r = 0; r < 4; r++) {
      float mt = m4[r];
      float iv = fsig(acc[0][r] + gxc[0 + r]);
      float fv = fsig(acc[1][r] + gxc[4 + r]);
      float gv = ftanh(acc[2][r] + gxc[8 + r]);
      float ov = fsig(acc[3][r] + gxc[12 + r]);
      unsigned hpw = hprev[r >> 1];
      union { uint32_t i; float f; } hu;
      hu.i = (r & 1) ? (hpw & 0xFFFF0000u) : (hpw << 16);
      float hpo = hu.f;
      float cn = fv * c_[r] + iv * gv;
      float hn = ov * ftanh(cn);
      hn = mt * hn + (1.f - mt) * hpo;
      cn = mt * cn + (1.f - mt) * c_[r];
      c_[r] = cn;
      hfv[r] = hn;
      unsigned hb = (unsigned)f2bf(hn) << ((r & 1) * 16);
      if (r < 2) p0 |= hb; else p1 |= hb;
    }

    // ---- ph5: publish h(s)
    // local: own 128 cols -> hls[wr] (read by ph1 next step)
#pragma unroll
    for (int r = 0; r < 4; r++) {
      u16 hb = (u16)(((r < 2) ? p0 : p1) >> ((r & 1) * 16));
      hwr[(q * 4 + r) * 264 + half * 128 + w * 16 + c16] = hb;
    }
    bar_lgkm();  // local h visible for readback (and for next step's ph1)

    // global: readback row-major u64 and store to hx slot (agent scope)
    {
      int row = tid >> 5, cg = tid & 31;
      unsigned long long v =
          *(const unsigned long long*)(hwr + row * 264 + half * 128 + cg * 4);
      __hip_atomic_store(
          &hx[((size_t)(pair * 2 + (s & 1)) * 2 + half) * 512 + row * 32 + cg], v,
          __ATOMIC_RELAXED, __HIP_MEMORY_SCOPE_AGENT);
    }
    // output stores
#pragma unroll
    for (int r = 0; r < 4; r++) {
      long oidx = ((long)((b0 + q * 4 + r) * 256 + t)) * 512 + d * 256 + ht * 16 + c16;
      if constexpr (OUTF32) outf[oidx] = hfv[r];
      else outh[oidx] = (u16)(((r < 2) ? p0 : p1) >> ((r & 1) * 16));
    }

    bar_vm();  // hx stores drained at agent scope before flag release
    if (tid == 0)
      __hip_atomic_store(&flags[s * 16 + pair * 2 + half], 1u, __ATOMIC_RELEASE,
                         __HIP_MEMORY_SCOPE_AGENT);

    hprev[0] = p0; hprev[1] = p1;
  }
}

// ============================================================================
extern "C" void kernel_launch(void* const* d_in, const int* in_sizes, int n_in,
                              void* d_out, int out_size, void* d_ws, size_t ws_size,
                              hipStream_t stream) {
  const int* iw = (const int*)d_in[0];
  const int* ic = (const int*)d_in[1];
  const int* ip = (const int*)d_in[2];
  const float* mask = (const float*)d_in[3];
  const float* ew = (const float*)d_in[4];
  const float* ec = (const float*)d_in[5];
  const float* ep = (const float*)d_in[6];
  const float* cw = (const float*)d_in[7];
  const float* cb = (const float*)d_in[8];
  const float* wih[3] = {(const float*)d_in[9], (const float*)d_in[12], (const float*)d_in[15]};
  const float* whh[3] = {(const float*)d_in[10], (const float*)d_in[13], (const float*)d_in[16]};
  const float* bs[3] = {(const float*)d_in[11], (const float*)d_in[14], (const float*)d_in[17]};

  char* ws = (char*)d_ws;
  size_t szX0 = (size_t)16384 * 512 * 2;
  size_t szGXf = (size_t)16384 * 2048 * 4;
  size_t szWIH = (size_t)2048 * 512 * 2;
  size_t szWHH = (size_t)2 * 1024 * 256 * 2;
  size_t szPROJ = 60032;
  size_t szHX = (size_t)8 * 2 * 2 * 4096;   // pairs x parity x half x 4KB = 128KB
  size_t szFLG = (size_t)256 * 16 * 4;      // per-step fresh flags, 16KB
  bool f32gx = ws_size >= szX0 + szGXf + szWIH + szWHH + szPROJ + szHX + szFLG;

  size_t off = 0;
  u16* X0 = (u16*)(ws + off); off += szX0;
  void* GX = (void*)(ws + off); off += f32gx ? szGXf : (szGXf / 2);
  u16* WIHB = (u16*)(ws + off); off += szWIH;
  u16* WHHB = (u16*)(ws + off); off += szWHH;
  u16* PROJ = (u16*)(ws + off); off += szPROJ;
  unsigned long long* HX = (unsigned long long*)(ws + off); off += szHX;
  unsigned* FLG = (unsigned*)(ws + off);
  u16* X1 = (u16*)d_out;  // bf16 staging in d_out; dead before final f32 write

  hipLaunchKernelGGL(k_proj, dim3(100), dim3(320), 0, stream, ec, cw, PROJ);
  hipLaunchKernelGGL(k_embed, dim3(16384), dim3(512), 0, stream, iw, ip, ew, ep, X0);
  hipLaunchKernelGGL(k_charconv, dim3(1024), dim3(128), 0, stream, ic, PROJ, cb, X0);

  const u16* Xin[3] = {X0, X1, X0};
  void* Xout[3] = {(void*)X1, (void*)X0, d_out};
  int Kin[3] = {500, 512, 512};

  for (int lyr = 0; lyr < 3; lyr++) {
    hipLaunchKernelGGL(k_cvt_wih, dim3(4096), dim3(256), 0, stream, wih[lyr], WIHB, Kin[lyr]);
    hipLaunchKernelGGL(k_cvt_whh, dim3(2048), dim3(256), 0, stream, whh[lyr], WHHB);
    hipMemsetAsync(FLG, 0, szFLG, stream);  // fresh flags per dispatch (replay-safe)
    if (f32gx) {
      hipLaunchKernelGGL((k_gemm<true>), dim3(16, 128), dim3(256), 0, stream,
                         Xin[lyr], WIHB, bs[lyr], GX);
      if (lyr < 2)
        hipLaunchKernelGGL((k_recur<true, false>), dim3(16), dim3(512), 0, stream,
                           GX, WHHB, mask, Xout[lyr], HX, FLG);
      else
        hipLaunchKernelGGL((k_recur<true, true>), dim3(16), dim3(512), 0, stream,
                           GX, WHHB, mask, Xout[lyr], HX, FLG);
    } else {
      hipLaunchKernelGGL((k_gemm<false>), dim3(16, 128), dim3(256), 0, stream,
                         Xin[lyr], WIHB, bs[lyr], GX);
      if (lyr < 2)
        hipLaunchKernelGGL((k_recur<false, false>), dim3(16), dim3(512), 0, stream,
                           GX, WHHB, mask, Xout[lyr], HX, FLG);
      else
        hipLaunchKernelGGL((k_recur<false, true>), dim3(16), dim3(512), 0, stream,
                           GX, WHHB, mask, Xout[lyr], HX, FLG);
    }
  }
}

// Round 6
// 2736.832 us; speedup vs baseline: 1.3523x; 1.3523x over previous
//
#include <hip/hip_runtime.h>
#include <cstdint>
#include <cstddef>
#include <type_traits>
#include <utility>

typedef unsigned short u16;
typedef short short8 __attribute__((ext_vector_type(8)));
typedef __bf16 bf16x8 __attribute__((ext_vector_type(8)));
typedef float float4v __attribute__((ext_vector_type(4)));

// ---------- bf16 <-> f32 ----------
__device__ __forceinline__ float bf2f(u16 u) {
  union { uint32_t i; float f; } v; v.i = ((uint32_t)u) << 16; return v.f;
}
__device__ __forceinline__ u16 f2bf(float f) {
  union { uint32_t i; float f; } v; v.f = f;
  uint32_t u = v.i;
  return (u16)((u + 0x7FFFu + ((u >> 16) & 1u)) >> 16);
}

// ---------- fast transcendentals (saturate cleanly at +-inf) ----------
__device__ __forceinline__ float fsig(float x) {
  float e = __expf(-x);
  return __builtin_amdgcn_rcpf(1.0f + e);
}
__device__ __forceinline__ float ftanh(float x) {
  float e = __expf(2.0f * x);
  return 1.0f - 2.0f * __builtin_amdgcn_rcpf(e + 1.0f);
}

// ---------- barriers ----------
__device__ __forceinline__ void bar_lgkm() {
  __builtin_amdgcn_sched_barrier(0);
  asm volatile("s_waitcnt lgkmcnt(0)" ::: "memory");
  __builtin_amdgcn_s_barrier();
  __builtin_amdgcn_sched_barrier(0);
}
// Execution-only barrier (no waitcnt): used after the flag poll so in-flight
// prefetch loads are NOT drained.
__device__ __forceinline__ void bar_only() {
  __builtin_amdgcn_sched_barrier(0);
  __builtin_amdgcn_s_barrier();
  __builtin_amdgcn_sched_barrier(0);
}
// Partial drain: hx store (issued before the 4 output stores) is proven
// retired at vmcnt(4); output stores keep streaming into the next step.
__device__ __forceinline__ void bar_vm4() {
  __builtin_amdgcn_sched_barrier(0);
  asm volatile("s_waitcnt vmcnt(4) lgkmcnt(0)" ::: "memory");
  __builtin_amdgcn_s_barrier();
  __builtin_amdgcn_sched_barrier(0);
}

// ---------- MFMA wrapper: works whether builtin takes short8 or bf16x8 ----------
template <class V, class = void> struct MfmaTakesShort : std::false_type {};
template <class V>
struct MfmaTakesShort<V, std::void_t<decltype(__builtin_amdgcn_mfma_f32_16x16x32_bf16(
    std::declval<V>(), std::declval<V>(), std::declval<float4v>(), 0, 0, 0))>>
    : std::true_type {};

template <bool UseShort> struct MF {
  template <class V>
  static __device__ __forceinline__ float4v run(V a, V b, float4v c) {
    return __builtin_amdgcn_mfma_f32_16x16x32_bf16(a, b, c, 0, 0, 0);
  }
};
template <> struct MF<false> {
  template <class V>
  static __device__ __forceinline__ float4v run(V a, V b, float4v c) {
    return __builtin_amdgcn_mfma_f32_16x16x32_bf16(
        __builtin_bit_cast(bf16x8, a), __builtin_bit_cast(bf16x8, b), c, 0, 0, 0);
  }
};
__device__ __forceinline__ float4v mfma_bf16(short8 a, short8 b, float4v c) {
  return MF<MfmaTakesShort<short8>::value>::run(a, b, c);
}

// ============================================================================
// Weight conversion: f32 [2048][Kin] -> bf16 [2048][512], zero-padded
// ============================================================================
__global__ void k_cvt_wih(const float* __restrict__ w, u16* __restrict__ o, int Kin) {
  int id = blockIdx.x * 256 + threadIdx.x;   // 2048*512 total
  int n = id >> 9, k = id & 511;
  o[id] = (k < Kin) ? f2bf(w[(long)n * Kin + k]) : (u16)0;
}

// f32 -> bf16 straight convert (w_hh: 2*1024*256 = 524288 elems)
__global__ void k_cvt_whh(const float* __restrict__ w, u16* __restrict__ o) {
  int id = blockIdx.x * 256 + threadIdx.x;
  o[id] = f2bf(w[id]);
}

// ============================================================================
// proj[v][k][nf] = sum_cd emb_char[v][cd] * conv_w[nf][cd][k]   (f32 in, bf16 out)
// ============================================================================
__global__ void k_proj(const float* __restrict__ ec, const float* __restrict__ cw,
                       u16* __restrict__ proj) {
  int v = blockIdx.x, idx = threadIdx.x;
  if (idx >= 300) return;
  int k = idx / 100, nf = idx % 100;
  float s = 0.f;
  for (int cd = 0; cd < 100; cd++)
    s += ec[v * 100 + cd] * cw[(nf * 100 + cd) * 3 + k];
  proj[v * 300 + k * 100 + nf] = f2bf(s);
}

// ============================================================================
// word + pos embedding gather into bf16 x (cols 0..299 word, 400..499 pos,
// 500..511 zero). Char features (300..399) filled by k_charconv.
// ============================================================================
__global__ void k_embed(const int* __restrict__ iw, const int* __restrict__ ip,
                        const float* __restrict__ ew, const float* __restrict__ ep,
                        u16* __restrict__ x) {
  int row = blockIdx.x, j = threadIdx.x;
  u16 v;
  if (j < 300) v = f2bf(ew[(long)iw[row] * 300 + j]);
  else if (j < 400) return;
  else if (j < 500) v = f2bf(ep[ip[row] * 100 + (j - 400)]);
  else v = 0;
  x[row * 512 + j] = v;
}

// ============================================================================
// char conv via proj table in LDS: out[nf] = tanh(b + max_p sum_k proj)
// ============================================================================
__global__ __launch_bounds__(128) void k_charconv(const int* __restrict__ ic,
                                                  const u16* __restrict__ proj,
                                                  const float* __restrict__ cb,
                                                  u16* __restrict__ x) {
  __shared__ u16 pl[30000];
  __shared__ int ids[20];
  int tid = threadIdx.x;
  for (int i = tid; i < 15000; i += 128)
    ((uint32_t*)pl)[i] = ((const uint32_t*)proj)[i];
  float bias = (tid < 100) ? cb[tid] : 0.f;
  for (int r = 0; r < 16; r++) {
    int row = blockIdx.x * 16 + r;
    __syncthreads();  // covers pl load on first iter; protects ids reuse
    if (tid < 20) ids[tid] = ic[row * 20 + tid];
    __syncthreads();
    if (tid < 100) {
      float mx = -1e30f;
      for (int p = 0; p < 22; p++) {
        float s = 0.f;
#pragma unroll
        for (int k = 0; k < 3; k++) {
          int q = p + k - 2;
          if (q >= 0 && q < 20) s += bf2f(pl[ids[q] * 300 + k * 100 + tid]);
        }
        mx = fmaxf(mx, s);
      }
      x[row * 512 + 300 + tid] = f2bf(ftanh(mx + bias));
    }
  }
}

// ============================================================================
// GEMM  C[16384 x 2048] = A[16384 x 512](bf16) @ B[2048 x 512]^T + bias(f32)
// 128x128 tile, BK=64, 4 waves, 16x16x32 MFMA. C fp32 (tier A) or bf16 (tier B).
// ============================================================================
template <bool GXF32>
__global__ __launch_bounds__(256) void k_gemm(const u16* __restrict__ A,
                                              const u16* __restrict__ Bm,
                                              const float* __restrict__ bias,
                                              void* __restrict__ Cv) {
  __shared__ u16 lA[128 * 64];
  __shared__ u16 lB[128 * 64];
  int tid = threadIdx.x;
  int w = tid >> 6, l = tid & 63, q = l >> 4, c16 = l & 15;
  int wm = w >> 1, wn = w & 1;
  int m0 = blockIdx.y * 128, n0 = blockIdx.x * 128;
  float4v acc[4][4];
#pragma unroll
  for (int i = 0; i < 4; i++)
#pragma unroll
    for (int j = 0; j < 4; j++) acc[i][j] = (float4v){0.f, 0.f, 0.f, 0.f};

  for (int kk = 0; kk < 512; kk += 64) {
    __syncthreads();
#pragma unroll
    for (int j = 0; j < 4; j++) {
      int idx = j * 256 + tid;
      int m = idx >> 3, k8 = (idx & 7) * 8;
      *(short8*)(lA + idx * 8) = *(const short8*)(A + (long)(m0 + m) * 512 + kk + k8);
      *(short8*)(lB + idx * 8) = *(const short8*)(Bm + (long)(n0 + m) * 512 + kk + k8);
    }
    __syncthreads();
#pragma unroll
    for (int kt = 0; kt < 2; kt++) {
      short8 af[4], bfv[4];
#pragma unroll
      for (int mt = 0; mt < 4; mt++)
        af[mt] = *(const short8*)(lA + (wm * 64 + mt * 16 + c16) * 64 + kt * 32 + q * 8);
#pragma unroll
      for (int nt = 0; nt < 4; nt++)
        bfv[nt] = *(const short8*)(lB + (wn * 64 + nt * 16 + c16) * 64 + kt * 32 + q * 8);
#pragma unroll
      for (int mt = 0; mt < 4; mt++)
#pragma unroll
        for (int nt = 0; nt < 4; nt++)
          acc[mt][nt] = mfma_bf16(af[mt], bfv[nt], acc[mt][nt]);
    }
  }
#pragma unroll
  for (int mt = 0; mt < 4; mt++)
#pragma unroll
    for (int nt = 0; nt < 4; nt++) {
      int ng = n0 + wn * 64 + nt * 16 + c16;
      float bv = bias[ng];
#pragma unroll
      for (int r = 0; r < 4; r++) {
        long mg = m0 + wm * 64 + mt * 16 + q * 4 + r;
        float val = acc[mt][nt][r] + bv;
        if constexpr (GXF32) ((float*)Cv)[mg * 2048 + ng] = val;
        else ((u16*)Cv)[mg * 2048 + ng] = f2bf(val);
      }
    }
}

// ============================================================================
// LSTM recurrence, COLUMN-SPLIT + SPLIT-K PIPELINE, COALESCED FRAG EXCHANGE.
// 16 blocks = 8 pairs (4 bg x 2 dir) x 2 halves; each block owns 128 h-cols.
//
// R5 (fixes R4's two regressions):
//  - R4's direct hx->A-frag loads were 256B-strided (64 cache lines per wave
//    instruction). Now the PRODUCER reorders its h-half into A-fragment order
//    via an LDS readback: hx[slot][ktl*128 + lane*2 + j] = u64 of
//    h[row=lane&15][local col ktl*32 + (lane>>4)*8 + j*4 .. +3].
//    The CONSUMER ingests with 8 perfectly coalesced u64 loads (1KB/wave/ktl)
//    and feeds them to MFMA directly from registers. No consumer LDS trip;
//    hls keeps own half only (2 x 16 x 136 u16 = 8.7KB).
//  - Ingest issued BEFORE gx loads: vmcnt is FIFO, so the compiler's
//    auto-wait at ph3 (partner MFMA) retires only the ingest; gx stays in
//    flight until ph4 (nonlin adds).
//  - End-of-step: hx store issued BEFORE the 4 output stores, then
//    s_waitcnt vmcnt(4) + barrier + flag release: hx proven retired, output
//    stores stream into the next step (no full vmcnt(0) drain).
// Phase order: poll(s-1)/bar_only -> ingest issue -> gx issue -> own-half-K
// MFMA -> partner-half-K MFMA (regs) -> nonlin(+gx) -> publish(ds_write own,
// bar_lgkm, readback->hx, out stores, vmcnt(4) bar, flag).
// Slot parity s&1; flags fresh per step (memset per dispatch, replay-safe);
// poll iteration-capped (sync bug -> absmax fail, not hang). Race-freedom:
// I overwrite slot (s&1) at s+2 only after observing partner flag(s+1),
// which partner sets only after its ingest of slot (s&1) at s+1.
// ============================================================================
template <bool GXF32, bool OUTF32>
__global__ __launch_bounds__(512, 2) void k_recur(
    const void* __restrict__ gxv, const u16* __restrict__ whh,
    const float* __restrict__ mask, void* __restrict__ outv,
    unsigned long long* __restrict__ hx, unsigned* __restrict__ flags) {
  __shared__ u16 hls[2][16 * 136];  // own half only; 136 stride == 264-class banking
  int tid = threadIdx.x;
  int w = tid >> 6, l = tid & 63, q = l >> 4, c16 = l & 15;
  int blk = blockIdx.x;
  int pair = blk & 7, half = blk >> 3;   // pair-mates land on same XCD
  int bg = pair >> 1, d = pair & 1;
  int b0 = bg * 16;
  int ht = half * 8 + w;                 // global h-coltile 0..15
  const u16* Wd = whh + d * (1024 * 256);

  for (int i = tid; i < 16 * 136; i += 512) hls[0][i] = 0;

  // B fragments: [g*8+j], j<4 own-half k-tiles, j>=4 partner-half k-tiles.
  short8 Breg[32];
#pragma unroll
  for (int g = 0; g < 4; g++)
#pragma unroll
    for (int j = 0; j < 8; j++) {
      int ktg = (j < 4) ? (half * 4 + j) : ((half ^ 1) * 4 + (j - 4));
      Breg[g * 8 + j] =
          *(const short8*)(Wd + ((g * 16 + ht) * 16 + c16) * 256 + ktg * 32 + q * 8);
    }

  float c_[4] = {0.f, 0.f, 0.f, 0.f};
  unsigned hprev[2] = {0u, 0u};  // packed bf16 of this lane's previous hn (4 rows)
  __syncthreads();

  const float* gxf = (const float*)gxv;
  const u16* gxh = (const u16*)gxv;
  float* outf = (float*)outv;
  u16* outh = (u16*)outv;

  // step-invariant per-lane element offsets (row-major GX), row = b0+q*4+r
  int rb[4];
#pragma unroll
  for (int r = 0; r < 4; r++)
    rb[r] = (b0 + q * 4 + r) * 524288 + d * 1024 + ht * 16 + c16;
  const float* mrow = mask + (b0 + q * 4) * 256;

#pragma unroll 1
  for (int s = 0; s < 256; s++) {
    int t = d ? (255 - s) : s;
    const u16* hrd = hls[s & 1];
    u16* hwr = hls[(s & 1) ^ 1];

    // ---- poll partner flag(s-1), then ingest partner A-frags (coalesced) --
    short8 png[4];  // partner h fragments, one per partner k-tile
    if (s > 0) {
      if (tid == 0) {
        unsigned idx = (unsigned)((s - 1) * 16 + pair * 2 + (half ^ 1));
        unsigned cnt = 0;
        while (__hip_atomic_load(&flags[idx], __ATOMIC_ACQUIRE,
                                 __HIP_MEMORY_SCOPE_AGENT) == 0u) {
          if (++cnt > 1000000u) break;  // fail visibly (absmax), don't hang
          __builtin_amdgcn_s_sleep(1);
        }
      }
      bar_only();  // no waitcnt
      const unsigned long long* ps =
          hx + ((size_t)(pair * 2 + ((s - 1) & 1)) * 2 + (half ^ 1)) * 512;
#pragma unroll
      for (int ktl = 0; ktl < 4; ktl++) {
        unsigned long long v0 = __hip_atomic_load(&ps[ktl * 128 + l * 2],
                                                  __ATOMIC_RELAXED,
                                                  __HIP_MEMORY_SCOPE_AGENT);
        unsigned long long v1 = __hip_atomic_load(&ps[ktl * 128 + l * 2 + 1],
                                                  __ATOMIC_RELAXED,
                                                  __HIP_MEMORY_SCOPE_AGENT);
        union { unsigned long long u[2]; short8 s8; } uu;
        uu.u[0] = v0; uu.u[1] = v1;
        png[ktl] = uu.s8;
      }
    }
    __builtin_amdgcn_sched_barrier(0);  // ingest issued before gx

    // ---- gx + mask loads; consumed in nonlin phase (adds) ----
    float m4[4];
#pragma unroll
    for (int r = 0; r < 4; r++) m4[r] = mrow[r * 256 + t];
    float gxc[16];  // [g*4+r]
    if constexpr (GXF32) {
      const float* gxs = gxf + (size_t)t * 2048;
#pragma unroll
      for (int r = 0; r < 4; r++) {
        const float* p = gxs + rb[r];
#pragma unroll
        for (int g = 0; g < 4; g++) gxc[g * 4 + r] = p[g * 256];  // imm offset
      }
    } else {
      const u16* gxs = gxh + (size_t)t * 2048;
#pragma unroll
      for (int r = 0; r < 4; r++) {
        const u16* p = gxs + rb[r];
#pragma unroll
        for (int g = 0; g < 4; g++) gxc[g * 4 + r] = bf2f(p[g * 256]);
      }
    }
    __builtin_amdgcn_sched_barrier(0);  // pin load issue above the MFMA body

    // ---- ph1: own-half-K MFMA (covers ingest + gx latency) ----
    float4v acc[4];
#pragma unroll
    for (int g = 0; g < 4; g++) acc[g] = (float4v){0.f, 0.f, 0.f, 0.f};
#pragma unroll
    for (int ktl = 0; ktl < 4; ktl++) {
      short8 a = *(const short8*)(hrd + c16 * 136 + ktl * 32 + q * 8);
#pragma unroll
      for (int g = 0; g < 4; g++)
        acc[g] = mfma_bf16(a, Breg[g * 8 + ktl], acc[g]);
    }

    // ---- ph3: partner-half-K MFMA straight from ingest registers ----
    if (s > 0) {
#pragma unroll
      for (int ktl = 0; ktl < 4; ktl++)
#pragma unroll
        for (int g = 0; g < 4; g++)
          acc[g] = mfma_bf16(png[ktl], Breg[g * 8 + 4 + ktl], acc[g]);
    }

    // ---- ph4: nonlinearity; gate = acc + gx ----
    unsigned p0 = 0u, p1 = 0u;
    float hfv[4];
#pragma unroll
    for (int r = 0; r < 4; r++) {
      float mt = m4[r];
      float iv = fsig(acc[0][r] + gxc[0 + r]);
      float fv = fsig(acc[1][r] + gxc[4 + r]);
      float gv = ftanh(acc[2][r] + gxc[8 + r]);
      float ov = fsig(acc[3][r] + gxc[12 + r]);
      unsigned hpw = hprev[r >> 1];
      union { uint32_t i; float f; } hu;
      hu.i = (r & 1) ? (hpw & 0xFFFF0000u) : (hpw << 16);
      float hpo = hu.f;
      float cn = fv * c_[r] + iv * gv;
      float hn = ov * ftanh(cn);
      hn = mt * hn + (1.f - mt) * hpo;
      cn = mt * cn + (1.f - mt) * c_[r];
      c_[r] = cn;
      hfv[r] = hn;
      unsigned hb = (unsigned)f2bf(hn) << ((r & 1) * 16);
      if (r < 2) p0 |= hb; else p1 |= hb;
    }

    // ---- ph5: publish h(s) ----
    if (s < 255) {
      // own h -> hls (local col = w*16+c16), read by next step's ph1
#pragma unroll
      for (int r = 0; r < 4; r++) {
        u16 hb = (u16)(((r < 2) ? p0 : p1) >> ((r & 1) * 16));
        hwr[(q * 4 + r) * 136 + w * 16 + c16] = hb;
      }
      bar_lgkm();  // all waves' own-h visible (for readback AND next ph1)

      // readback in A-frag order -> hx (coalesced u64 store per thread)
      {
        int ktl2 = tid >> 7, ll = (tid >> 1) & 63, j = tid & 1;
        int qq = ll >> 4, cc = ll & 15;
        unsigned long long v =
            *(const unsigned long long*)(hwr + cc * 136 + ktl2 * 32 + qq * 8 + j * 4);
        __hip_atomic_store(
            &hx[((size_t)(pair * 2 + (s & 1)) * 2 + half) * 512 + tid], v,
            __ATOMIC_RELAXED, __HIP_MEMORY_SCOPE_AGENT);
      }
      __builtin_amdgcn_sched_barrier(0);  // hx store before out stores
      // output stores (4/thread; drain in background past the barrier)
#pragma unroll
      for (int r = 0; r < 4; r++) {
        long oidx = ((long)((b0 + q * 4 + r) * 256 + t)) * 512 + d * 256 + ht * 16 + c16;
        if constexpr (OUTF32) outf[oidx] = hfv[r];
        else outh[oidx] = (u16)(((r < 2) ? p0 : p1) >> ((r & 1) * 16));
      }
      bar_vm4();  // hx retired (4 newest = out stores may linger)
      if (tid == 0)
        __hip_atomic_store(&flags[s * 16 + pair * 2 + half], 1u, __ATOMIC_RELEASE,
                           __HIP_MEMORY_SCOPE_AGENT);
    } else {
      // last step: outputs only
#pragma unroll
      for (int r = 0; r < 4; r++) {
        long oidx = ((long)((b0 + q * 4 + r) * 256 + t)) * 512 + d * 256 + ht * 16 + c16;
        if constexpr (OUTF32) outf[oidx] = hfv[r];
        else outh[oidx] = (u16)(((r < 2) ? p0 : p1) >> ((r & 1) * 16));
      }
    }

    hprev[0] = p0; hprev[1] = p1;
  }
}

// ============================================================================
extern "C" void kernel_launch(void* const* d_in, const int* in_sizes, int n_in,
                              void* d_out, int out_size, void* d_ws, size_t ws_size,
                              hipStream_t stream) {
  const int* iw = (const int*)d_in[0];
  const int* ic = (const int*)d_in[1];
  const int* ip = (const int*)d_in[2];
  const float* mask = (const float*)d_in[3];
  const float* ew = (const float*)d_in[4];
  const float* ec = (const float*)d_in[5];
  const float* ep = (const float*)d_in[6];
  const float* cw = (const float*)d_in[7];
  const float* cb = (const float*)d_in[8];
  const float* wih[3] = {(const float*)d_in[9], (const float*)d_in[12], (const float*)d_in[15]};
  const float* whh[3] = {(const float*)d_in[10], (const float*)d_in[13], (const float*)d_in[16]};
  const float* bs[3] = {(const float*)d_in[11], (const float*)d_in[14], (const float*)d_in[17]};

  char* ws = (char*)d_ws;
  size_t szX0 = (size_t)16384 * 512 * 2;
  size_t szGXf = (size_t)16384 * 2048 * 4;
  size_t szWIH = (size_t)2048 * 512 * 2;
  size_t szWHH = (size_t)2 * 1024 * 256 * 2;
  size_t szPROJ = 60032;
  size_t szHX = (size_t)8 * 2 * 2 * 4096;   // pairs x parity x half x 4KB = 128KB
  size_t szFLG = (size_t)256 * 16 * 4;      // per-step fresh flags, 16KB
  bool f32gx = ws_size >= szX0 + szGXf + szWIH + szWHH + szPROJ + szHX + szFLG;

  size_t off = 0;
  u16* X0 = (u16*)(ws + off); off += szX0;
  void* GX = (void*)(ws + off); off += f32gx ? szGXf : (szGXf / 2);
  u16* WIHB = (u16*)(ws + off); off += szWIH;
  u16* WHHB = (u16*)(ws + off); off += szWHH;
  u16* PROJ = (u16*)(ws + off); off += szPROJ;
  unsigned long long* HX = (unsigned long long*)(ws + off); off += szHX;
  unsigned* FLG = (unsigned*)(ws + off);
  u16* X1 = (u16*)d_out;  // bf16 staging in d_out; dead before final f32 write

  hipLaunchKernelGGL(k_proj, dim3(100), dim3(320), 0, stream, ec, cw, PROJ);
  hipLaunchKernelGGL(k_embed, dim3(16384), dim3(512), 0, stream, iw, ip, ew, ep, X0);
  hipLaunchKernelGGL(k_charconv, dim3(1024), dim3(128), 0, stream, ic, PROJ, cb, X0);

  const u16* Xin[3] = {X0, X1, X0};
  void* Xout[3] = {(void*)X1, (void*)X0, d_out};
  int Kin[3] = {500, 512, 512};

  for (int lyr = 0; lyr < 3; lyr++) {
    hipLaunchKernelGGL(k_cvt_wih, dim3(4096), dim3(256), 0, stream, wih[lyr], WIHB, Kin[lyr]);
    hipLaunchKernelGGL(k_cvt_whh, dim3(2048), dim3(256), 0, stream, whh[lyr], WHHB);
    hipMemsetAsync(FLG, 0, szFLG, stream);  // fresh flags per dispatch (replay-safe)
    if (f32gx) {
      hipLaunchKernelGGL((k_gemm<true>), dim3(16, 128), dim3(256), 0, stream,
                         Xin[lyr], WIHB, bs[lyr], GX);
      if (lyr < 2)
        hipLaunchKernelGGL((k_recur<true, false>), dim3(16), dim3(512), 0, stream,
                           GX, WHHB, mask, Xout[lyr], HX, FLG);
      else
        hipLaunchKernelGGL((k_recur<true, true>), dim3(16), dim3(512), 0, stream,
                           GX, WHHB, mask, Xout[lyr], HX, FLG);
    } else {
      hipLaunchKernelGGL((k_gemm<false>), dim3(16, 128), dim3(256), 0, stream,
                         Xin[lyr], WIHB, bs[lyr], GX);
      if (lyr < 2)
        hipLaunchKernelGGL((k_recur<false, false>), dim3(16), dim3(512), 0, stream,
                           GX, WHHB, mask, Xout[lyr], HX, FLG);
      else
        hipLaunchKernelGGL((k_recur<false, true>), dim3(16), dim3(512), 0, stream,
                           GX, WHHB, mask, Xout[lyr], HX, FLG);
    }
  }
}

// Round 7
// 2641.782 us; speedup vs baseline: 1.4010x; 1.0360x over previous
//
#include <hip/hip_runtime.h>
#include <cstdint>
#include <cstddef>
#include <type_traits>
#include <utility>

typedef unsigned short u16;
typedef short short8 __attribute__((ext_vector_type(8)));
typedef __bf16 bf16x8 __attribute__((ext_vector_type(8)));
typedef float float4v __attribute__((ext_vector_type(4)));

// ---------- bf16 <-> f32 ----------
__device__ __forceinline__ float bf2f(u16 u) {
  union { uint32_t i; float f; } v; v.i = ((uint32_t)u) << 16; return v.f;
}
__device__ __forceinline__ u16 f2bf(float f) {
  union { uint32_t i; float f; } v; v.f = f;
  uint32_t u = v.i;
  return (u16)((u + 0x7FFFu + ((u >> 16) & 1u)) >> 16);
}

// ---------- fast transcendentals (saturate cleanly at +-inf) ----------
__device__ __forceinline__ float fsig(float x) {
  float e = __expf(-x);
  return __builtin_amdgcn_rcpf(1.0f + e);
}
__device__ __forceinline__ float ftanh(float x) {
  float e = __expf(2.0f * x);
  return 1.0f - 2.0f * __builtin_amdgcn_rcpf(e + 1.0f);
}

// ---------- MFMA wrapper: works whether builtin takes short8 or bf16x8 ----------
template <class V, class = void> struct MfmaTakesShort : std::false_type {};
template <class V>
struct MfmaTakesShort<V, std::void_t<decltype(__builtin_amdgcn_mfma_f32_16x16x32_bf16(
    std::declval<V>(), std::declval<V>(), std::declval<float4v>(), 0, 0, 0))>>
    : std::true_type {};

template <bool UseShort> struct MF {
  template <class V>
  static __device__ __forceinline__ float4v run(V a, V b, float4v c) {
    return __builtin_amdgcn_mfma_f32_16x16x32_bf16(a, b, c, 0, 0, 0);
  }
};
template <> struct MF<false> {
  template <class V>
  static __device__ __forceinline__ float4v run(V a, V b, float4v c) {
    return __builtin_amdgcn_mfma_f32_16x16x32_bf16(
        __builtin_bit_cast(bf16x8, a), __builtin_bit_cast(bf16x8, b), c, 0, 0, 0);
  }
};
__device__ __forceinline__ float4v mfma_bf16(short8 a, short8 b, float4v c) {
  return MF<MfmaTakesShort<short8>::value>::run(a, b, c);
}

// ============================================================================
// Weight conversion: f32 [2048][Kin] -> bf16 [2048][512], zero-padded
// ============================================================================
__global__ void k_cvt_wih(const float* __restrict__ w, u16* __restrict__ o, int Kin) {
  int id = blockIdx.x * 256 + threadIdx.x;   // 2048*512 total
  int n = id >> 9, k = id & 511;
  o[id] = (k < Kin) ? f2bf(w[(long)n * Kin + k]) : (u16)0;
}

// f32 -> bf16 straight convert (w_hh: 2*1024*256 = 524288 elems)
__global__ void k_cvt_whh(const float* __restrict__ w, u16* __restrict__ o) {
  int id = blockIdx.x * 256 + threadIdx.x;
  o[id] = f2bf(w[id]);
}

// ============================================================================
// proj[v][k][nf] = sum_cd emb_char[v][cd] * conv_w[nf][cd][k]   (f32 in, bf16 out)
// ============================================================================
__global__ void k_proj(const float* __restrict__ ec, const float* __restrict__ cw,
                       u16* __restrict__ proj) {
  int v = blockIdx.x, idx = threadIdx.x;
  if (idx >= 300) return;
  int k = idx / 100, nf = idx % 100;
  float s = 0.f;
  for (int cd = 0; cd < 100; cd++)
    s += ec[v * 100 + cd] * cw[(nf * 100 + cd) * 3 + k];
  proj[v * 300 + k * 100 + nf] = f2bf(s);
}

// ============================================================================
// word + pos embedding gather into bf16 x (cols 0..299 word, 400..499 pos,
// 500..511 zero). Char features (300..399) filled by k_charconv.
// ============================================================================
__global__ void k_embed(const int* __restrict__ iw, const int* __restrict__ ip,
                        const float* __restrict__ ew, const float* __restrict__ ep,
                        u16* __restrict__ x) {
  int row = blockIdx.x, j = threadIdx.x;
  u16 v;
  if (j < 300) v = f2bf(ew[(long)iw[row] * 300 + j]);
  else if (j < 400) return;
  else if (j < 500) v = f2bf(ep[ip[row] * 100 + (j - 400)]);
  else v = 0;
  x[row * 512 + j] = v;
}

// ============================================================================
// char conv via proj table in LDS: out[nf] = tanh(b + max_p sum_k proj)
// ============================================================================
__global__ __launch_bounds__(128) void k_charconv(const int* __restrict__ ic,
                                                  const u16* __restrict__ proj,
                                                  const float* __restrict__ cb,
                                                  u16* __restrict__ x) {
  __shared__ u16 pl[30000];
  __shared__ int ids[20];
  int tid = threadIdx.x;
  for (int i = tid; i < 15000; i += 128)
    ((uint32_t*)pl)[i] = ((const uint32_t*)proj)[i];
  float bias = (tid < 100) ? cb[tid] : 0.f;
  for (int r = 0; r < 16; r++) {
    int row = blockIdx.x * 16 + r;
    __syncthreads();  // covers pl load on first iter; protects ids reuse
    if (tid < 20) ids[tid] = ic[row * 20 + tid];
    __syncthreads();
    if (tid < 100) {
      float mx = -1e30f;
      for (int p = 0; p < 22; p++) {
        float s = 0.f;
#pragma unroll
        for (int k = 0; k < 3; k++) {
          int q = p + k - 2;
          if (q >= 0 && q < 20) s += bf2f(pl[ids[q] * 300 + k * 100 + tid]);
        }
        mx = fmaxf(mx, s);
      }
      x[row * 512 + 300 + tid] = f2bf(ftanh(mx + bias));
    }
  }
}

// ============================================================================
// GEMM  C[16384 x 2048] = A[16384 x 512](bf16) @ B[2048 x 512]^T + bias(f32)
// 128x128 tile, BK=64, 4 waves, 16x16x32 MFMA. C fp32 (tier A) or bf16 (tier B).
// ============================================================================
template <bool GXF32>
__global__ __launch_bounds__(256) void k_gemm(const u16* __restrict__ A,
                                              const u16* __restrict__ Bm,
                                              const float* __restrict__ bias,
                                              void* __restrict__ Cv) {
  __shared__ u16 lA[128 * 64];
  __shared__ u16 lB[128 * 64];
  int tid = threadIdx.x;
  int w = tid >> 6, l = tid & 63, q = l >> 4, c16 = l & 15;
  int wm = w >> 1, wn = w & 1;
  int m0 = blockIdx.y * 128, n0 = blockIdx.x * 128;
  float4v acc[4][4];
#pragma unroll
  for (int i = 0; i < 4; i++)
#pragma unroll
    for (int j = 0; j < 4; j++) acc[i][j] = (float4v){0.f, 0.f, 0.f, 0.f};

  for (int kk = 0; kk < 512; kk += 64) {
    __syncthreads();
#pragma unroll
    for (int j = 0; j < 4; j++) {
      int idx = j * 256 + tid;
      int m = idx >> 3, k8 = (idx & 7) * 8;
      *(short8*)(lA + idx * 8) = *(const short8*)(A + (long)(m0 + m) * 512 + kk + k8);
      *(short8*)(lB + idx * 8) = *(const short8*)(Bm + (long)(n0 + m) * 512 + kk + k8);
    }
    __syncthreads();
#pragma unroll
    for (int kt = 0; kt < 2; kt++) {
      short8 af[4], bfv[4];
#pragma unroll
      for (int mt = 0; mt < 4; mt++)
        af[mt] = *(const short8*)(lA + (wm * 64 + mt * 16 + c16) * 64 + kt * 32 + q * 8);
#pragma unroll
      for (int nt = 0; nt < 4; nt++)
        bfv[nt] = *(const short8*)(lB + (wn * 64 + nt * 16 + c16) * 64 + kt * 32 + q * 8);
#pragma unroll
      for (int mt = 0; mt < 4; mt++)
#pragma unroll
        for (int nt = 0; nt < 4; nt++)
          acc[mt][nt] = mfma_bf16(af[mt], bfv[nt], acc[mt][nt]);
    }
  }
#pragma unroll
  for (int mt = 0; mt < 4; mt++)
#pragma unroll
    for (int nt = 0; nt < 4; nt++) {
      int ng = n0 + wn * 64 + nt * 16 + c16;
      float bv = bias[ng];
#pragma unroll
      for (int r = 0; r < 4; r++) {
        long mg = m0 + wm * 64 + mt * 16 + q * 4 + r;
        float val = acc[mt][nt][r] + bv;
        if constexpr (GXF32) ((float*)Cv)[mg * 2048 + ng] = val;
        else ((u16*)Cv)[mg * 2048 + ng] = f2bf(val);
      }
    }
}

// ============================================================================
// LSTM recurrence, COLUMN-SPLIT + SPLIT-K PIPELINE + SWAPPED-OPERAND MFMA.
// 16 blocks = 8 pairs (4 bg x 2 dir) x 2 halves; each block owns 128 h-cols.
//
// R6: compute gates^T = mfma(A=W, B=h) instead of mfma(h, W). A- and B-frag
// per-lane layouts are identical (idx=l&15, k=(l>>4)*8+j), so Breg loads and
// the hls b128 reads are UNCHANGED — only the argument order swaps. The D
// layout (col=l&15=batch row, row=(l>>4)*4+r=gate-col) makes each lane own
// 1 batch row x 4 CONSECUTIVE h-cols:
//   - h publish = one ds_write_b64 (no LDS readback transpose; barrier gone)
//   - hx layout [colgroup4][row]: producer store AND consumer ingest coalesced
//   - gx = 4 x float4 (was 16 scalar), mask = 1 load (was 4), out = 1 vector
//     store (was 4 scattered), hprev = one u64
// Pipelining: gx(t+1)+mask(t+1) issued in ph5 (consumed next ph4, ~1500cy
// cover). Per-wave flag poll (atomic loads bypass L1) -> no poll barrier.
// One barrier/step: [hx store; sched_fence; out+gx_next+mask_next;
// s_waitcnt vmcnt(6) lgkmcnt(0); s_barrier; tid0 relaxed flag store].
// Ordering: all waves' hx stores proven retired (vmcnt) before the barrier;
// flag store issues after -> flag visible implies hx visible (L2/LLC, atomic
// path). Poll/ingest are L1-bypassing relaxed atomics. Poll iteration-capped
// -> a sync bug fails absmax instead of hanging. Slot parity s&1; flags fresh
// per dispatch (memset, replay-safe).
// ============================================================================
template <bool GXF32, bool OUTF32>
__global__ __launch_bounds__(512, 2) void k_recur(
    const void* __restrict__ gxv, const u16* __restrict__ whh,
    const float* __restrict__ mask, void* __restrict__ outv,
    unsigned long long* __restrict__ hx, unsigned* __restrict__ flags) {
  __shared__ u16 hls[2][16 * 136];  // own half only, [row][col] row-major
  int tid = threadIdx.x;
  int w = tid >> 6, l = tid & 63;
  int row = l & 15;        // batch row within block (D col = l&15)
  int cg = l >> 4;         // col-group; lane owns cols c4..c4+3 of its tile
  int c4 = cg * 4;
  int blk = blockIdx.x;
  int pair = blk & 7, half = blk >> 3;   // pair-mates land on same XCD
  int bg = pair >> 1, d = pair & 1;
  int b0 = bg * 16;
  int ht = half * 8 + w;                 // global h-coltile 0..15
  const u16* Wd = whh + d * (1024 * 256);

  for (int i = tid; i < 16 * 136; i += 512) hls[0][i] = 0;

  // B fragments (UNCHANGED from R5 — same per-lane data, now used as the
  // A operand): [g*8+j], j<4 own-half k-tiles, j>=4 partner-half k-tiles.
  short8 Breg[32];
#pragma unroll
  for (int g = 0; g < 4; g++)
#pragma unroll
    for (int j = 0; j < 8; j++) {
      int ktg = (j < 4) ? (half * 4 + j) : ((half ^ 1) * 4 + (j - 4));
      Breg[g * 8 + j] =
          *(const short8*)(Wd + ((g * 16 + ht) * 16 + row) * 256 + ktg * 32 + cg * 8);
    }

  float c_[4] = {0.f, 0.f, 0.f, 0.f};
  unsigned long long hp64 = 0ull;  // this lane's previous 4 h-values (bf16 x4)
  __syncthreads();

  const float* gxf = (const float*)gxv;
  const u16* gxh = (const u16*)gxv;
  float* outf = (float*)outv;
  u16* outh = (u16*)outv;

  // lane-invariant bases
  int grow = b0 + row;                                   // global batch row
  const float* mrowp = mask + grow * 256;
  size_t gxbase = (size_t)grow * 524288 + d * 1024 + ht * 16 + c4;
  long obase = ((long)grow * 256) * 512 + d * 256 + ht * 16 + c4;

  using GxT = std::conditional_t<GXF32, float4v, unsigned long long>;
  GxT gxc[4], gxn[4];
  float mcur, mnxt;

  // preamble: load gx(t0) + mask(t0)
  {
    int t0 = d ? 255 : 0;
    mcur = mrowp[t0];
#pragma unroll
    for (int g = 0; g < 4; g++) {
      if constexpr (GXF32)
        gxc[g] = *(const float4v*)(gxf + gxbase + (size_t)t0 * 2048 + g * 256);
      else
        gxc[g] = *(const unsigned long long*)(gxh + gxbase + (size_t)t0 * 2048 + g * 256);
    }
  }

#pragma unroll 1
  for (int s = 0; s < 256; s++) {
    int t = d ? (255 - s) : s;
    const u16* hrd = hls[s & 1];
    u16* hwr = hls[(s & 1) ^ 1];

    // ---- poll partner flag(s-1) (per-wave; atomic loads bypass L1), ingest
    short8 png[4];
    if (s > 0) {
      unsigned fidx = (unsigned)((s - 1) * 16 + pair * 2 + (half ^ 1));
      unsigned cnt = 0;
      while (__hip_atomic_load(&flags[fidx], __ATOMIC_RELAXED,
                               __HIP_MEMORY_SCOPE_AGENT) == 0u) {
        if (++cnt > 1000000u) break;  // fail visibly (absmax), don't hang
        __builtin_amdgcn_s_sleep(1);
      }
      const unsigned long long* ps =
          hx + ((size_t)(pair * 2 + ((s - 1) & 1)) * 2 + (half ^ 1)) * 512;
#pragma unroll
      for (int ktl = 0; ktl < 4; ktl++) {
        unsigned long long v0 = __hip_atomic_load(
            &ps[(ktl * 8 + cg * 2 + 0) * 16 + row], __ATOMIC_RELAXED,
            __HIP_MEMORY_SCOPE_AGENT);
        unsigned long long v1 = __hip_atomic_load(
            &ps[(ktl * 8 + cg * 2 + 1) * 16 + row], __ATOMIC_RELAXED,
            __HIP_MEMORY_SCOPE_AGENT);
        union { unsigned long long u[2]; short8 s8; } uu;
        uu.u[0] = v0; uu.u[1] = v1;
        png[ktl] = uu.s8;
      }
    }
    __builtin_amdgcn_sched_barrier(0);  // ingest issued early

    // ---- ph1: own-half-K MFMA (W as A, h as B) ----
    float4v acc[4];
#pragma unroll
    for (int g = 0; g < 4; g++) acc[g] = (float4v){0.f, 0.f, 0.f, 0.f};
#pragma unroll
    for (int ktl = 0; ktl < 4; ktl++) {
      short8 b = *(const short8*)(hrd + row * 136 + ktl * 32 + cg * 8);
#pragma unroll
      for (int g = 0; g < 4; g++)
        acc[g] = mfma_bf16(Breg[g * 8 + ktl], b, acc[g]);
    }
    // ---- ph3: partner-half-K MFMA from ingest registers ----
    if (s > 0) {
#pragma unroll
      for (int ktl = 0; ktl < 4; ktl++)
#pragma unroll
        for (int g = 0; g < 4; g++)
          acc[g] = mfma_bf16(Breg[g * 8 + 4 + ktl], png[ktl], acc[g]);
    }

    // ---- ph4: nonlinearity; lane owns row `grow`, h-cols ht*16+c4..+3 ----
    float mt = mcur, mo = 1.f - mcur;
    float hnv[4];
    unsigned long long hn64 = 0ull;
#pragma unroll
    for (int r = 0; r < 4; r++) {
      float gi, gf, gg, go;
      if constexpr (GXF32) {
        gi = gxc[0][r]; gf = gxc[1][r]; gg = gxc[2][r]; go = gxc[3][r];
      } else {
        gi = bf2f((u16)(gxc[0] >> (r * 16)));
        gf = bf2f((u16)(gxc[1] >> (r * 16)));
        gg = bf2f((u16)(gxc[2] >> (r * 16)));
        go = bf2f((u16)(gxc[3] >> (r * 16)));
      }
      float iv = fsig(acc[0][r] + gi);
      float fv = fsig(acc[1][r] + gf);
      float gv = ftanh(acc[2][r] + gg);
      float ov = fsig(acc[3][r] + go);
      float hpo = bf2f((u16)(hp64 >> (r * 16)));
      float cn = fv * c_[r] + iv * gv;
      float hn = ov * ftanh(cn);
      hn = mt * hn + mo * hpo;
      cn = mt * cn + mo * c_[r];
      c_[r] = cn;
      hnv[r] = hn;
      hn64 |= ((unsigned long long)f2bf(hn)) << (r * 16);
    }

    // ---- ph5: publish h(s), outputs, prefetch gx(t+1) ----
    if (s < 255) {
      // hx store FIRST (oldest VMEM op -> proven retired at vmcnt(6))
      __hip_atomic_store(
          &hx[((size_t)(pair * 2 + (s & 1)) * 2 + half) * 512 + (w * 4 + cg) * 16 + row],
          hn64, __ATOMIC_RELAXED, __HIP_MEMORY_SCOPE_AGENT);
      __builtin_amdgcn_sched_barrier(0);
      // own h -> hls (one b64; read by next step's ph1 b128s)
      *(unsigned long long*)(hwr + row * 136 + w * 16 + c4) = hn64;
      // output store (single vector op)
      if constexpr (OUTF32) {
        float4v ov4 = {hnv[0], hnv[1], hnv[2], hnv[3]};
        *(float4v*)(outf + obase + (long)t * 512) = ov4;
      } else {
        *(unsigned long long*)(outh + obase + (long)t * 512) = hn64;
      }
      // prefetch next-step gx + mask (consumed next ph4; ~full-step cover)
      int tn = d ? (254 - s) : (s + 1);
      mnxt = mrowp[tn];
#pragma unroll
      for (int g = 0; g < 4; g++) {
        if constexpr (GXF32)
          gxn[g] = *(const float4v*)(gxf + gxbase + (size_t)tn * 2048 + g * 256);
        else
          gxn[g] = *(const unsigned long long*)(gxh + gxbase + (size_t)tn * 2048 + g * 256);
      }
      __builtin_amdgcn_sched_barrier(0);
      // hx proven retired (6 newer VMEM: out + 4 gx + mask may still fly)
      asm volatile("s_waitcnt vmcnt(6) lgkmcnt(0)" ::: "memory");
      __builtin_amdgcn_s_barrier();
      __builtin_amdgcn_sched_barrier(0);
      if (tid == 0)
        __hip_atomic_store(&flags[s * 16 + pair * 2 + half], 1u, __ATOMIC_RELAXED,
                           __HIP_MEMORY_SCOPE_AGENT);
#pragma unroll
      for (int g = 0; g < 4; g++) gxc[g] = gxn[g];
      mcur = mnxt;
    } else {
      // last step: outputs only
      if constexpr (OUTF32) {
        float4v ov4 = {hnv[0], hnv[1], hnv[2], hnv[3]};
        *(float4v*)(outf + obase + (long)t * 512) = ov4;
      } else {
        *(unsigned long long*)(outh + obase + (long)t * 512) = hn64;
      }
    }
    hp64 = hn64;
  }
}

// ============================================================================
extern "C" void kernel_launch(void* const* d_in, const int* in_sizes, int n_in,
                              void* d_out, int out_size, void* d_ws, size_t ws_size,
                              hipStream_t stream) {
  const int* iw = (const int*)d_in[0];
  const int* ic = (const int*)d_in[1];
  const int* ip = (const int*)d_in[2];
  const float* mask = (const float*)d_in[3];
  const float* ew = (const float*)d_in[4];
  const float* ec = (const float*)d_in[5];
  const float* ep = (const float*)d_in[6];
  const float* cw = (const float*)d_in[7];
  const float* cb = (const float*)d_in[8];
  const float* wih[3] = {(const float*)d_in[9], (const float*)d_in[12], (const float*)d_in[15]};
  const float* whh[3] = {(const float*)d_in[10], (const float*)d_in[13], (const float*)d_in[16]};
  const float* bs[3] = {(const float*)d_in[11], (const float*)d_in[14], (const float*)d_in[17]};

  char* ws = (char*)d_ws;
  size_t szX0 = (size_t)16384 * 512 * 2;
  size_t szGXf = (size_t)16384 * 2048 * 4;
  size_t szWIH = (size_t)2048 * 512 * 2;
  size_t szWHH = (size_t)2 * 1024 * 256 * 2;
  size_t szPROJ = 60032;
  size_t szHX = (size_t)8 * 2 * 2 * 4096;   // pairs x parity x half x 4KB = 128KB
  size_t szFLG = (size_t)256 * 16 * 4;      // per-step fresh flags, 16KB
  bool f32gx = ws_size >= szX0 + szGXf + szWIH + szWHH + szPROJ + szHX + szFLG;

  size_t off = 0;
  u16* X0 = (u16*)(ws + off); off += szX0;
  void* GX = (void*)(ws + off); off += f32gx ? szGXf : (szGXf / 2);
  u16* WIHB = (u16*)(ws + off); off += szWIH;
  u16* WHHB = (u16*)(ws + off); off += szWHH;
  u16* PROJ = (u16*)(ws + off); off += szPROJ;
  unsigned long long* HX = (unsigned long long*)(ws + off); off += szHX;
  unsigned* FLG = (unsigned*)(ws + off);
  u16* X1 = (u16*)d_out;  // bf16 staging in d_out; dead before final f32 write

  hipLaunchKernelGGL(k_proj, dim3(100), dim3(320), 0, stream, ec, cw, PROJ);
  hipLaunchKernelGGL(k_embed, dim3(16384), dim3(512), 0, stream, iw, ip, ew, ep, X0);
  hipLaunchKernelGGL(k_charconv, dim3(1024), dim3(128), 0, stream, ic, PROJ, cb, X0);

  const u16* Xin[3] = {X0, X1, X0};
  void* Xout[3] = {(void*)X1, (void*)X0, d_out};
  int Kin[3] = {500, 512, 512};

  for (int lyr = 0; lyr < 3; lyr++) {
    hipLaunchKernelGGL(k_cvt_wih, dim3(4096), dim3(256), 0, stream, wih[lyr], WIHB, Kin[lyr]);
    hipLaunchKernelGGL(k_cvt_whh, dim3(2048), dim3(256), 0, stream, whh[lyr], WHHB);
    hipMemsetAsync(FLG, 0, szFLG, stream);  // fresh flags per dispatch (replay-safe)
    if (f32gx) {
      hipLaunchKernelGGL((k_gemm<true>), dim3(16, 128), dim3(256), 0, stream,
                         Xin[lyr], WIHB, bs[lyr], GX);
      if (lyr < 2)
        hipLaunchKernelGGL((k_recur<true, false>), dim3(16), dim3(512), 0, stream,
                           GX, WHHB, mask, Xout[lyr], HX, FLG);
      else
        hipLaunchKernelGGL((k_recur<true, true>), dim3(16), dim3(512), 0, stream,
                           GX, WHHB, mask, Xout[lyr], HX, FLG);
    } else {
      hipLaunchKernelGGL((k_gemm<false>), dim3(16, 128), dim3(256), 0, stream,
                         Xin[lyr], WIHB, bs[lyr], GX);
      if (lyr < 2)
        hipLaunchKernelGGL((k_recur<false, false>), dim3(16), dim3(512), 0, stream,
                           GX, WHHB, mask, Xout[lyr], HX, FLG);
      else
        hipLaunchKernelGGL((k_recur<false, true>), dim3(16), dim3(512), 0, stream,
                           GX, WHHB, mask, Xout[lyr], HX, FLG);
    }
  }
}